// Round 8
// baseline (8647.980 us; speedup 1.0000x reference)
//
#include <hip/hip_runtime.h>
#include <stdint.h>

#define H_ 1024
#define NG_ 4096   // 4*H

typedef float f32x4 __attribute__((ext_vector_type(4)));
typedef __bf16 bf16x8 __attribute__((ext_vector_type(8)));

__device__ __forceinline__ unsigned short f2bf(float f) {
  union { float f; uint32_t u; } v; v.f = f;
  uint32_t r = v.u + 0x7FFFu + ((v.u >> 16) & 1u);
  return (unsigned short)(r >> 16);
}
__device__ __forceinline__ float bf2f(unsigned short b) {
  union { uint32_t u; float f; } v; v.u = ((uint32_t)b) << 16; return v.f;
}

__device__ __forceinline__ void gload_lds16(const void* g, void* l) {
  __builtin_amdgcn_global_load_lds(
      (const __attribute__((address_space(1))) void*)g,
      (__attribute__((address_space(3))) void*)l, 16, 0, 0);
}

__device__ __forceinline__ float sigm(float x) { return 1.f / (1.f + __expf(-x)); }
__device__ __forceinline__ float tanh_(float x) { return 1.f - 2.f / (__expf(2.f * x) + 1.f); }

// ---------------------------------------------------------------------------
// Weight prep: permute rows r = (j>>4)*64 + gate*16 + (j&15)  (old = gate*H + j)
// so a 64-wide column group holds 16 units x 4 gates, gate index = n-frag index.
// ---------------------------------------------------------------------------
__global__ void prep_w0(const float* __restrict__ Whh0, unsigned short* __restrict__ Wr) {
  int i = (blockIdx.x * 256 + threadIdx.x) * 4;           // over 4096*1024
  int r = i >> 10, k = i & 1023;
  int gate = (r >> 4) & 3;
  int j = ((r >> 6) << 4) + (r & 15);
  const float4 v = *(const float4*)(Whh0 + (size_t)(gate * H_ + j) * H_ + k);
  ushort4 o; o.x = f2bf(v.x); o.y = f2bf(v.y); o.z = f2bf(v.z); o.w = f2bf(v.w);
  *(ushort4*)(Wr + i) = o;
}

__global__ void prep_wcat(const float* __restrict__ Wih1, const float* __restrict__ Whh1,
                          unsigned short* __restrict__ Wr) {
  int i = (blockIdx.x * 256 + threadIdx.x) * 4;           // over 4096*2048
  int r = i >> 11, k = i & 2047;
  int gate = (r >> 4) & 3;
  int j = ((r >> 6) << 4) + (r & 15);
  const float* src = (k < 1024) ? (Wih1 + (size_t)(gate * H_ + j) * H_ + k)
                                : (Whh1 + (size_t)(gate * H_ + j) * H_ + (k - 1024));
  const float4 v = *(const float4*)src;
  ushort4 o; o.x = f2bf(v.x); o.y = f2bf(v.y); o.z = f2bf(v.z); o.w = f2bf(v.w);
  *(ushort4*)(Wr + (size_t)r * 2048 + k) = o;
}

__global__ void prep_small(const float* __restrict__ Wih0,
                           const float* __restrict__ bih0, const float* __restrict__ bhh0,
                           const float* __restrict__ bih1, const float* __restrict__ bhh1,
                           float* __restrict__ bias0r, float* __restrict__ bias1r,
                           float* __restrict__ wi0r) {
  int r = blockIdx.x * 256 + threadIdx.x;                 // over 4096
  int gate = (r >> 4) & 3;
  int j = ((r >> 6) << 4) + (r & 15);
  int old = gate * H_ + j;
  bias0r[r] = bih0[old] + bhh0[old];
  bias1r[r] = bih1[old] + bhh1[old];
  wi0r[r * 2 + 0] = Wih0[old * 2 + 0];
  wi0r[r * 2 + 1] = Wih0[old * 2 + 1];
}

__global__ void prep_state(const float* __restrict__ h, const float* __restrict__ c,
                           unsigned short* __restrict__ h0b, unsigned short* __restrict__ h1b,
                           float* __restrict__ c0, float* __restrict__ c1, int bh) {
  int i = (blockIdx.x * 256 + threadIdx.x) * 4;           // over B*H
  float4 a = *(const float4*)(h + i);
  float4 b = *(const float4*)(h + (size_t)bh + i);
  ushort4 oa; oa.x = f2bf(a.x); oa.y = f2bf(a.y); oa.z = f2bf(a.z); oa.w = f2bf(a.w);
  ushort4 ob; ob.x = f2bf(b.x); ob.y = f2bf(b.y); ob.z = f2bf(b.z); ob.w = f2bf(b.w);
  *(ushort4*)(h0b + i) = oa;
  *(ushort4*)(h1b + i) = ob;
  *(float4*)(c0 + i) = *(const float4*)(c + i);
  *(float4*)(c1 + i) = *(const float4*)(c + (size_t)bh + i);
}

// ---------------------------------------------------------------------------
// Fused GEMM + LSTM cell (+ optional fused fc head).
// R7 structure: 128x128 tile, BK=64, 4 waves, single-buffered LDS, 4 blocks/CU
// occupancy-pipelined, both-sides XOR swizzle (slot ^= row&7, 16B slots).
// New in R8:
//  - XCD-aware blockIdx swizzle (8 XCDs x 128 contiguous blocks -> A-panel
//    stays in the XCD's L2).
//  - If fcW != null: epilogue computes logits partials hn*fcW, shfl-reduces
//    over the 16 unit-lanes, atomicAdds into outT[row*pl2 + c] (f32).
//    Bias added once by the (tile_n==0, wn==0) wave. Replaces fc_argmax.
//  - If xlog != null: x = xlog[row*pl2+1] > xlog[row*pl2] (prev step logits,
//    bias already included).
// ---------------------------------------------------------------------------
__global__ void __launch_bounds__(256, 4)
lstm_gemm_cell(const unsigned short* __restrict__ A0,
               const unsigned short* __restrict__ A1,
               int Ktot,
               const unsigned short* __restrict__ Bw,
               const float* __restrict__ biasr,
               const float* __restrict__ wi0r,
               const float* __restrict__ xlog,
               float* __restrict__ Cst,
               unsigned short* __restrict__ Hout,
               const float* __restrict__ fcW,
               const float* __restrict__ fcb,
               float* __restrict__ outT,
               int pl2) {
  __shared__ unsigned short As[128 * 64];
  __shared__ unsigned short Bs[128 * 64];
  const int tid  = threadIdx.x;
  const int lane = tid & 63;
  const int wv   = tid >> 6;
  const int wm   = wv >> 1, wn = wv & 1;

  // XCD-aware swizzle: nwg = 32*32 = 1024, 128 contiguous blocks per XCD.
  const int wgid = blockIdx.y * 32 + blockIdx.x;
  const int swz  = ((wgid & 7) << 7) | (wgid >> 3);
  const int tile_m = (swz >> 5) * 128;
  const int tile_n = (swz & 31) * 128;

  f32x4 acc[4][4];
#pragma unroll
  for (int m = 0; m < 4; ++m)
#pragma unroll
    for (int n = 0; n < 4; ++n) acc[m][n] = (f32x4)0.f;

  // staging: chunk = 8 rows x 64 cols; lane covers row lane>>3, slot lane&7.
  // dest is linear (base + lane*16); source col slot pre-XORed by row&7.
  const int lrow = lane >> 3;                      // row within chunk (= row&7)
  const int lk   = ((lane & 7) ^ lrow) * 8;        // inv-swizzled global col (elems)

  const int nk = Ktot >> 6;
  for (int kt = 0; kt < nk; ++kt) {
    const int k0 = kt << 6;
    const unsigned short* Ap; int kl;
    if (k0 < 1024) { Ap = A0; kl = k0; } else { Ap = A1; kl = k0 - 1024; }
#pragma unroll
    for (int i = 0; i < 4; ++i) {
      int chunk = wv * 4 + i;
      int row = chunk * 8 + lrow;
      gload_lds16(Ap + (size_t)(tile_m + row) * H_ + kl + lk, (void*)&As[chunk * 512]);
    }
#pragma unroll
    for (int i = 0; i < 4; ++i) {
      int chunk = wv * 4 + i;
      int row = chunk * 8 + lrow;
      gload_lds16(Bw + (size_t)(tile_n + row) * Ktot + k0 + lk, (void*)&Bs[chunk * 512]);
    }
    __syncthreads();

    const char* Ab = (const char*)As;
    const char* Bb = (const char*)Bs;
    const int arow = wm * 64 + (lane & 15);
    const int brow = wn * 64 + (lane & 15);
    const int khi  = lane >> 4;                    // 0..3
    const int x7   = lane & 7;                     // row&7 of the rows this lane reads
    const int ksw0 = ((0 + khi) ^ x7) * 16;        // physical byte off, ks=0
    const int ksw1 = ((4 + khi) ^ x7) * 16;        // ks=1
#pragma unroll
    for (int ks = 0; ks < 2; ++ks) {
      const int ksw = ks ? ksw1 : ksw0;
      bf16x8 af[4], bfr[4];
#pragma unroll
      for (int m = 0; m < 4; ++m)
        af[m] = *(const bf16x8*)(Ab + (arow + m * 16) * 128 + ksw);
#pragma unroll
      for (int n = 0; n < 4; ++n)
        bfr[n] = *(const bf16x8*)(Bb + (brow + n * 16) * 128 + ksw);
#pragma unroll
      for (int m = 0; m < 4; ++m)
#pragma unroll
        for (int n = 0; n < 4; ++n)
          acc[m][n] = __builtin_amdgcn_mfma_f32_16x16x32_bf16(af[m], bfr[n], acc[m][n], 0, 0, 0);
    }
    __syncthreads();
  }

  // ---- epilogue: fused LSTM cell (+ optional fc head) ----
  const int cl = lane & 15;
  const int rq = (lane >> 4) * 4;
  const int jgrp = (tile_n >> 6) + wn;             // (tile_n + wn*64)/64
  const int j = jgrp * 16 + cl;
  float bias[4], w0v[4] = {0, 0, 0, 0}, w1v[4] = {0, 0, 0, 0};
  const int have_x = (xlog != nullptr);
#pragma unroll
  for (int n = 0; n < 4; ++n) {
    int colr = tile_n + wn * 64 + n * 16 + cl;
    bias[n] = biasr[colr];
    if (have_x) { w0v[n] = wi0r[colr * 2]; w1v[n] = wi0r[colr * 2 + 1]; }
  }
  float fW0 = 0.f, fW1 = 0.f;
  if (fcW) { fW0 = fcW[j]; fW1 = fcW[H_ + j]; }
  const int add_bias = (tile_n == 0) && (wn == 0);

#pragma unroll
  for (int m = 0; m < 4; ++m) {
#pragma unroll
    for (int q = 0; q < 4; ++q) {
      int row = tile_m + wm * 64 + m * 16 + rq + q;
      float gi = acc[m][0][q] + bias[0];
      float gf = acc[m][1][q] + bias[1];
      float gg = acc[m][2][q] + bias[2];
      float go = acc[m][3][q] + bias[3];
      if (have_x) {
        const float* xr = xlog + (size_t)row * pl2;
        int x = xr[1] > xr[0];
        gi += x ? w1v[0] : w0v[0];
        gf += x ? w1v[1] : w0v[1];
        gg += x ? w1v[2] : w0v[2];
        go += x ? w1v[3] : w0v[3];
      }
      size_t off = (size_t)row * H_ + j;
      float cp = Cst[off];
      float cn = sigm(gf) * cp + sigm(gi) * tanh_(gg);
      float hn = sigm(go) * tanh_(cn);
      Cst[off] = cn;
      Hout[off] = f2bf(hn);
      if (fcW) {
        float d0 = hn * fW0, d1 = hn * fW1;
#pragma unroll
        for (int s = 1; s < 16; s <<= 1) {
          d0 += __shfl_xor(d0, s);
          d1 += __shfl_xor(d1, s);
        }
        if (cl == 0) {
          if (add_bias) { d0 += fcb[0]; d1 += fcb[1]; }
          float* op = outT + (size_t)row * pl2;
          atomicAdd(op, d0);
          atomicAdd(op + 1, d1);
        }
      }
    }
  }
}

// ---------------------------------------------------------------------------
extern "C" void kernel_launch(void* const* d_in, const int* in_sizes, int n_in,
                              void* d_out, int out_size, void* d_ws, size_t ws_size,
                              hipStream_t stream) {
  const float* h     = (const float*)d_in[0];
  const float* c     = (const float*)d_in[1];
  const float* Wih0  = (const float*)d_in[2];
  const float* Whh0  = (const float*)d_in[3];
  const float* bih0  = (const float*)d_in[4];
  const float* bhh0  = (const float*)d_in[5];
  const float* Wih1  = (const float*)d_in[6];
  const float* Whh1  = (const float*)d_in[7];
  const float* bih1  = (const float*)d_in[8];
  const float* bhh1  = (const float*)d_in[9];
  const float* fcW   = (const float*)d_in[10];
  const float* fcb   = (const float*)d_in[11];

  const int B = in_sizes[0] / (2 * H_);           // 4096
  const int pred_len = out_size / (B * 2);        // 64
  const int BH = B * H_;                          // 4194304
  const int pl2 = pred_len * 2;

  size_t off = 0;
  auto carve = [&](size_t bytes) -> void* {
    void* p = (char*)d_ws + off;
    off += (bytes + 255) & ~(size_t)255;
    return p;
  };
  unsigned short* Whh0r = (unsigned short*)carve((size_t)NG_ * 1024 * 2);
  unsigned short* Wcatr = (unsigned short*)carve((size_t)NG_ * 2048 * 2);
  unsigned short* h0b[2], *h1b[2];
  h0b[0] = (unsigned short*)carve((size_t)BH * 2);
  h0b[1] = (unsigned short*)carve((size_t)BH * 2);
  h1b[0] = (unsigned short*)carve((size_t)BH * 2);
  h1b[1] = (unsigned short*)carve((size_t)BH * 2);
  float* c0 = (float*)carve((size_t)BH * 4);
  float* c1 = (float*)carve((size_t)BH * 4);
  float* bias0r = (float*)carve(NG_ * 4);
  float* bias1r = (float*)carve(NG_ * 4);
  float* wi0r   = (float*)carve(NG_ * 2 * 4);

  // d_out is accumulated via atomics each call -> zero it inside the graph.
  hipMemsetAsync(d_out, 0, (size_t)out_size * sizeof(float), stream);

  hipLaunchKernelGGL(prep_w0,   dim3((NG_ * 1024 / 4) / 256), dim3(256), 0, stream, Whh0, Whh0r);
  hipLaunchKernelGGL(prep_wcat, dim3((NG_ * 2048 / 4) / 256), dim3(256), 0, stream, Wih1, Whh1, Wcatr);
  hipLaunchKernelGGL(prep_small, dim3(NG_ / 256), dim3(256), 0, stream,
                     Wih0, bih0, bhh0, bih1, bhh1, bias0r, bias1r, wi0r);
  hipLaunchKernelGGL(prep_state, dim3((BH / 4) / 256), dim3(256), 0, stream,
                     h, c, h0b[0], h1b[0], c0, c1, BH);

  dim3 ggrid(NG_ / 128, B / 128);                 // 32 x 32 = 1024 blocks
  dim3 gblk(256);
  float* out = (float*)d_out;

  for (int t = 0; t < pred_len; ++t) {
    const int cur = t & 1, nxt = cur ^ 1;
    // layer 0: gates = h0 @ Whh0^T + bias (+ Wih0[:,x] from prev logits)
    hipLaunchKernelGGL(lstm_gemm_cell, ggrid, gblk, 0, stream,
                       h0b[cur], (const unsigned short*)nullptr, 1024, Whh0r,
                       bias0r, wi0r,
                       (t > 0) ? (out + (size_t)(t - 1) * 2) : (const float*)nullptr,
                       c0, h0b[nxt],
                       (const float*)nullptr, (const float*)nullptr, (float*)nullptr, pl2);
    // layer 1: gates = [h0n|h1] @ Wcat^T + bias; fused fc head -> out slot t
    hipLaunchKernelGGL(lstm_gemm_cell, ggrid, gblk, 0, stream,
                       h0b[nxt], h1b[cur], 2048, Wcatr,
                       bias1r, (const float*)nullptr,
                       (const float*)nullptr,
                       c1, h1b[nxt],
                       fcW, fcb, out + (size_t)t * 2, pl2);
  }
}

// Round 9
// 7676.807 us; speedup vs baseline: 1.1265x; 1.1265x over previous
//
#include <hip/hip_runtime.h>
#include <stdint.h>

#define H_ 1024
#define NG_ 4096   // 4*H

typedef float f32x4 __attribute__((ext_vector_type(4)));
typedef __bf16 bf16x8 __attribute__((ext_vector_type(8)));

__device__ __forceinline__ unsigned short f2bf(float f) {
  union { float f; uint32_t u; } v; v.f = f;
  uint32_t r = v.u + 0x7FFFu + ((v.u >> 16) & 1u);
  return (unsigned short)(r >> 16);
}
__device__ __forceinline__ float bf2f(unsigned short b) {
  union { uint32_t u; float f; } v; v.u = ((uint32_t)b) << 16; return v.f;
}

__device__ __forceinline__ void gload_lds16(const void* g, void* l) {
  __builtin_amdgcn_global_load_lds(
      (const __attribute__((address_space(1))) void*)g,
      (__attribute__((address_space(3))) void*)l, 16, 0, 0);
}

__device__ __forceinline__ float sigm(float x) { return 1.f / (1.f + __expf(-x)); }
__device__ __forceinline__ float tanh_(float x) { return 1.f - 2.f / (__expf(2.f * x) + 1.f); }

// ---------------------------------------------------------------------------
// Weight prep: permute rows r = (j>>4)*64 + gate*16 + (j&15)  (old = gate*H + j)
// so a 64-wide column group holds 16 units x 4 gates, gate index = n-frag index.
// ---------------------------------------------------------------------------
__global__ void prep_w0(const float* __restrict__ Whh0, unsigned short* __restrict__ Wr) {
  int i = (blockIdx.x * 256 + threadIdx.x) * 4;           // over 4096*1024
  int r = i >> 10, k = i & 1023;
  int gate = (r >> 4) & 3;
  int j = ((r >> 6) << 4) + (r & 15);
  const float4 v = *(const float4*)(Whh0 + (size_t)(gate * H_ + j) * H_ + k);
  ushort4 o; o.x = f2bf(v.x); o.y = f2bf(v.y); o.z = f2bf(v.z); o.w = f2bf(v.w);
  *(ushort4*)(Wr + i) = o;
}

__global__ void prep_wcat(const float* __restrict__ Wih1, const float* __restrict__ Whh1,
                          unsigned short* __restrict__ Wr) {
  int i = (blockIdx.x * 256 + threadIdx.x) * 4;           // over 4096*2048
  int r = i >> 11, k = i & 2047;
  int gate = (r >> 4) & 3;
  int j = ((r >> 6) << 4) + (r & 15);
  const float* src = (k < 1024) ? (Wih1 + (size_t)(gate * H_ + j) * H_ + k)
                                : (Whh1 + (size_t)(gate * H_ + j) * H_ + (k - 1024));
  const float4 v = *(const float4*)src;
  ushort4 o; o.x = f2bf(v.x); o.y = f2bf(v.y); o.z = f2bf(v.z); o.w = f2bf(v.w);
  *(ushort4*)(Wr + (size_t)r * 2048 + k) = o;
}

__global__ void prep_small(const float* __restrict__ Wih0,
                           const float* __restrict__ bih0, const float* __restrict__ bhh0,
                           const float* __restrict__ bih1, const float* __restrict__ bhh1,
                           float* __restrict__ bias0r, float* __restrict__ bias1r,
                           float* __restrict__ wi0r) {
  int r = blockIdx.x * 256 + threadIdx.x;                 // over 4096
  int gate = (r >> 4) & 3;
  int j = ((r >> 6) << 4) + (r & 15);
  int old = gate * H_ + j;
  bias0r[r] = bih0[old] + bhh0[old];
  bias1r[r] = bih1[old] + bhh1[old];
  wi0r[r * 2 + 0] = Wih0[old * 2 + 0];
  wi0r[r * 2 + 1] = Wih0[old * 2 + 1];
}

__global__ void prep_state(const float* __restrict__ h, const float* __restrict__ c,
                           unsigned short* __restrict__ h0b, unsigned short* __restrict__ h1b,
                           float* __restrict__ c0, float* __restrict__ c1, int bh) {
  int i = (blockIdx.x * 256 + threadIdx.x) * 4;           // over B*H
  float4 a = *(const float4*)(h + i);
  float4 b = *(const float4*)(h + (size_t)bh + i);
  ushort4 oa; oa.x = f2bf(a.x); oa.y = f2bf(a.y); oa.z = f2bf(a.z); oa.w = f2bf(a.w);
  ushort4 ob; ob.x = f2bf(b.x); ob.y = f2bf(b.y); ob.z = f2bf(b.z); ob.w = f2bf(b.w);
  *(ushort4*)(h0b + i) = oa;
  *(ushort4*)(h1b + i) = ob;
  *(float4*)(c0 + i) = *(const float4*)(c + i);
  *(float4*)(c1 + i) = *(const float4*)(c + (size_t)bh + i);
}

// ---------------------------------------------------------------------------
// Fused GEMM + LSTM cell (R7 structure: 128x128 tile, BK=64, 4 waves,
// single-buffered swizzled LDS, default block order = best XCD locality).
// R9 fc fusion (atomic-free):
//  - L1 (fcW != null): epilogue shfl-reduces hn*fcW over the 16 unit-lanes and
//    writes per-(row, 16-unit-slot) partials to fcpart_out[row*128 + slot*2+c].
//  - L0, t>=1 (fcpart_in != null): at kernel start, threads 0..127 reduce the
//    128 partials of row tile_m+tid, write the PREVIOUS step's logits to
//    outPrev[row*pl2 + c], and cache x=argmax flag in LDS for the epilogue's
//    W_ih0 column-select.
// ---------------------------------------------------------------------------
__global__ void __launch_bounds__(256, 4)
lstm_gemm_cell(const unsigned short* __restrict__ A0,
               const unsigned short* __restrict__ A1,
               int Ktot,
               const unsigned short* __restrict__ Bw,
               const float* __restrict__ biasr,
               const float* __restrict__ wi0r,
               const float* __restrict__ fcpart_in,
               const float* __restrict__ fcb,
               float* __restrict__ outPrev,
               int pl2,
               float* __restrict__ Cst,
               unsigned short* __restrict__ Hout,
               const float* __restrict__ fcW,
               float* __restrict__ fcpart_out) {
  __shared__ unsigned short As[128 * 64];
  __shared__ unsigned short Bs[128 * 64];
  __shared__ unsigned char xflag[128];
  const int tid  = threadIdx.x;
  const int lane = tid & 63;
  const int wv   = tid >> 6;
  const int wm   = wv >> 1, wn = wv & 1;
  const int tile_m = blockIdx.y * 128;
  const int tile_n = blockIdx.x * 128;

  // ---- L0 prologue: reduce previous step's fc partials -> x flags + logits ----
  const int have_x = (fcpart_in != nullptr);
  if (have_x && tid < 128) {
    const int row = tile_m + tid;
    const float* fp = fcpart_in + (size_t)row * 128;
    float s0 = 0.f, s1 = 0.f;
#pragma unroll
    for (int i2 = 0; i2 < 32; ++i2) {
      float4 v = *(const float4*)(fp + i2 * 4);
      s0 += v.x + v.z; s1 += v.y + v.w;
    }
    s0 += fcb[0]; s1 += fcb[1];
    outPrev[(size_t)row * pl2 + 0] = s0;
    outPrev[(size_t)row * pl2 + 1] = s1;
    xflag[tid] = (s1 > s0) ? 1 : 0;
  }
  // (visibility of xflag guaranteed by the K-loop's __syncthreads below)

  f32x4 acc[4][4];
#pragma unroll
  for (int m = 0; m < 4; ++m)
#pragma unroll
    for (int n = 0; n < 4; ++n) acc[m][n] = (f32x4)0.f;

  // staging: chunk = 8 rows x 64 cols; dest linear, source col slot ^= row&7.
  const int lrow = lane >> 3;
  const int lk   = ((lane & 7) ^ lrow) * 8;

  const int nk = Ktot >> 6;
  for (int kt = 0; kt < nk; ++kt) {
    const int k0 = kt << 6;
    const unsigned short* Ap; int kl;
    if (k0 < 1024) { Ap = A0; kl = k0; } else { Ap = A1; kl = k0 - 1024; }
#pragma unroll
    for (int i = 0; i < 4; ++i) {
      int chunk = wv * 4 + i;
      int row = chunk * 8 + lrow;
      gload_lds16(Ap + (size_t)(tile_m + row) * H_ + kl + lk, (void*)&As[chunk * 512]);
    }
#pragma unroll
    for (int i = 0; i < 4; ++i) {
      int chunk = wv * 4 + i;
      int row = chunk * 8 + lrow;
      gload_lds16(Bw + (size_t)(tile_n + row) * Ktot + k0 + lk, (void*)&Bs[chunk * 512]);
    }
    __syncthreads();

    const char* Ab = (const char*)As;
    const char* Bb = (const char*)Bs;
    const int arow = wm * 64 + (lane & 15);
    const int brow = wn * 64 + (lane & 15);
    const int khi  = lane >> 4;
    const int x7   = lane & 7;
    const int ksw0 = ((0 + khi) ^ x7) * 16;
    const int ksw1 = ((4 + khi) ^ x7) * 16;
#pragma unroll
    for (int ks = 0; ks < 2; ++ks) {
      const int ksw = ks ? ksw1 : ksw0;
      bf16x8 af[4], bfr[4];
#pragma unroll
      for (int m = 0; m < 4; ++m)
        af[m] = *(const bf16x8*)(Ab + (arow + m * 16) * 128 + ksw);
#pragma unroll
      for (int n = 0; n < 4; ++n)
        bfr[n] = *(const bf16x8*)(Bb + (brow + n * 16) * 128 + ksw);
#pragma unroll
      for (int m = 0; m < 4; ++m)
#pragma unroll
        for (int n = 0; n < 4; ++n)
          acc[m][n] = __builtin_amdgcn_mfma_f32_16x16x32_bf16(af[m], bfr[n], acc[m][n], 0, 0, 0);
    }
    __syncthreads();
  }

  // ---- epilogue: fused LSTM cell (+ optional fc partials) ----
  const int cl = lane & 15;
  const int rq = (lane >> 4) * 4;
  const int jgrp = (tile_n >> 6) + wn;             // 16-unit slot index, 0..63
  const int j = jgrp * 16 + cl;
  float bias[4], w0v[4] = {0, 0, 0, 0}, w1v[4] = {0, 0, 0, 0};
#pragma unroll
  for (int n = 0; n < 4; ++n) {
    int colr = tile_n + wn * 64 + n * 16 + cl;
    bias[n] = biasr[colr];
    if (have_x) { w0v[n] = wi0r[colr * 2]; w1v[n] = wi0r[colr * 2 + 1]; }
  }
  float fW0 = 0.f, fW1 = 0.f;
  if (fcW) { fW0 = fcW[j]; fW1 = fcW[H_ + j]; }

#pragma unroll
  for (int m = 0; m < 4; ++m) {
#pragma unroll
    for (int q = 0; q < 4; ++q) {
      int row = tile_m + wm * 64 + m * 16 + rq + q;
      float gi = acc[m][0][q] + bias[0];
      float gf = acc[m][1][q] + bias[1];
      float gg = acc[m][2][q] + bias[2];
      float go = acc[m][3][q] + bias[3];
      if (have_x) {
        int x = xflag[row - tile_m];
        gi += x ? w1v[0] : w0v[0];
        gf += x ? w1v[1] : w0v[1];
        gg += x ? w1v[2] : w0v[2];
        go += x ? w1v[3] : w0v[3];
      }
      size_t off = (size_t)row * H_ + j;
      float cp = Cst[off];
      float cn = sigm(gf) * cp + sigm(gi) * tanh_(gg);
      float hn = sigm(go) * tanh_(cn);
      Cst[off] = cn;
      Hout[off] = f2bf(hn);
      if (fcW) {
        float d0 = hn * fW0, d1 = hn * fW1;
#pragma unroll
        for (int s = 1; s < 16; s <<= 1) {
          d0 += __shfl_xor(d0, s);
          d1 += __shfl_xor(d1, s);
        }
        if (cl == 0) {
          float2 p; p.x = d0; p.y = d1;
          *(float2*)(fcpart_out + (size_t)row * 128 + jgrp * 2) = p;
        }
      }
    }
  }
}

// ---------------------------------------------------------------------------
// final step's fc: reduce partials -> out[:, pred_len-1, :]
// ---------------------------------------------------------------------------
__global__ void fc_finalize(const float* __restrict__ fcpart, const float* __restrict__ fcb,
                            float* __restrict__ outLast, int pl2) {
  const int row = blockIdx.x * 256 + threadIdx.x;
  const float* fp = fcpart + (size_t)row * 128;
  float s0 = 0.f, s1 = 0.f;
#pragma unroll
  for (int i2 = 0; i2 < 32; ++i2) {
    float4 v = *(const float4*)(fp + i2 * 4);
    s0 += v.x + v.z; s1 += v.y + v.w;
  }
  outLast[(size_t)row * pl2 + 0] = s0 + fcb[0];
  outLast[(size_t)row * pl2 + 1] = s1 + fcb[1];
}

// ---------------------------------------------------------------------------
extern "C" void kernel_launch(void* const* d_in, const int* in_sizes, int n_in,
                              void* d_out, int out_size, void* d_ws, size_t ws_size,
                              hipStream_t stream) {
  const float* h     = (const float*)d_in[0];
  const float* c     = (const float*)d_in[1];
  const float* Wih0  = (const float*)d_in[2];
  const float* Whh0  = (const float*)d_in[3];
  const float* bih0  = (const float*)d_in[4];
  const float* bhh0  = (const float*)d_in[5];
  const float* Wih1  = (const float*)d_in[6];
  const float* Whh1  = (const float*)d_in[7];
  const float* bih1  = (const float*)d_in[8];
  const float* bhh1  = (const float*)d_in[9];
  const float* fcW   = (const float*)d_in[10];
  const float* fcb   = (const float*)d_in[11];

  const int B = in_sizes[0] / (2 * H_);           // 4096
  const int pred_len = out_size / (B * 2);        // 64
  const int BH = B * H_;                          // 4194304
  const int pl2 = pred_len * 2;

  size_t off = 0;
  auto carve = [&](size_t bytes) -> void* {
    void* p = (char*)d_ws + off;
    off += (bytes + 255) & ~(size_t)255;
    return p;
  };
  unsigned short* Whh0r = (unsigned short*)carve((size_t)NG_ * 1024 * 2);
  unsigned short* Wcatr = (unsigned short*)carve((size_t)NG_ * 2048 * 2);
  unsigned short* h0b[2], *h1b[2];
  h0b[0] = (unsigned short*)carve((size_t)BH * 2);
  h0b[1] = (unsigned short*)carve((size_t)BH * 2);
  h1b[0] = (unsigned short*)carve((size_t)BH * 2);
  h1b[1] = (unsigned short*)carve((size_t)BH * 2);
  float* c0 = (float*)carve((size_t)BH * 4);
  float* c1 = (float*)carve((size_t)BH * 4);
  float* bias0r = (float*)carve(NG_ * 4);
  float* bias1r = (float*)carve(NG_ * 4);
  float* wi0r   = (float*)carve(NG_ * 2 * 4);
  float* fcpart = (float*)carve((size_t)B * 128 * 4);   // 2 MB

  hipLaunchKernelGGL(prep_w0,   dim3((NG_ * 1024 / 4) / 256), dim3(256), 0, stream, Whh0, Whh0r);
  hipLaunchKernelGGL(prep_wcat, dim3((NG_ * 2048 / 4) / 256), dim3(256), 0, stream, Wih1, Whh1, Wcatr);
  hipLaunchKernelGGL(prep_small, dim3(NG_ / 256), dim3(256), 0, stream,
                     Wih0, bih0, bhh0, bih1, bhh1, bias0r, bias1r, wi0r);
  hipLaunchKernelGGL(prep_state, dim3((BH / 4) / 256), dim3(256), 0, stream,
                     h, c, h0b[0], h1b[0], c0, c1, BH);

  dim3 ggrid(NG_ / 128, B / 128);                 // 32 x 32 = 1024 blocks
  dim3 gblk(256);
  float* out = (float*)d_out;

  for (int t = 0; t < pred_len; ++t) {
    const int cur = t & 1, nxt = cur ^ 1;
    // layer 0: gates = h0 @ Whh0^T + bias (+ Wih0[:,x]); also reduces prev fc
    hipLaunchKernelGGL(lstm_gemm_cell, ggrid, gblk, 0, stream,
                       h0b[cur], (const unsigned short*)nullptr, 1024, Whh0r,
                       bias0r, wi0r,
                       (t > 0) ? (const float*)fcpart : (const float*)nullptr,
                       fcb,
                       (t > 0) ? (out + (size_t)(t - 1) * 2) : (float*)nullptr,
                       pl2,
                       c0, h0b[nxt],
                       (const float*)nullptr, (float*)nullptr);
    // layer 1: gates = [h0n|h1] @ Wcat^T + bias; fc partials -> fcpart
    hipLaunchKernelGGL(lstm_gemm_cell, ggrid, gblk, 0, stream,
                       h0b[nxt], h1b[cur], 2048, Wcatr,
                       bias1r, (const float*)nullptr,
                       (const float*)nullptr, (const float*)nullptr,
                       (float*)nullptr, pl2,
                       c1, h1b[nxt],
                       fcW, fcpart);
  }
  hipLaunchKernelGGL(fc_finalize, dim3(B / 256), dim3(256), 0, stream,
                     fcpart, fcb, out + (size_t)(pred_len - 1) * 2, pl2);
}

// Round 10
// 7465.912 us; speedup vs baseline: 1.1583x; 1.0282x over previous
//
#include <hip/hip_runtime.h>
#include <stdint.h>

#define H_ 1024
#define NG_ 4096   // 4*H

typedef float f32x4 __attribute__((ext_vector_type(4)));
typedef __bf16 bf16x8 __attribute__((ext_vector_type(8)));

__device__ __forceinline__ unsigned short f2bf(float f) {
  union { float f; uint32_t u; } v; v.f = f;
  uint32_t r = v.u + 0x7FFFu + ((v.u >> 16) & 1u);
  return (unsigned short)(r >> 16);
}
__device__ __forceinline__ float bf2f(unsigned short b) {
  union { uint32_t u; float f; } v; v.u = ((uint32_t)b) << 16; return v.f;
}

__device__ __forceinline__ void gload_lds16(const void* g, void* l) {
  __builtin_amdgcn_global_load_lds(
      (const __attribute__((address_space(1))) void*)g,
      (__attribute__((address_space(3))) void*)l, 16, 0, 0);
}

__device__ __forceinline__ float sigm(float x) { return 1.f / (1.f + __expf(-x)); }
__device__ __forceinline__ float tanh_(float x) { return 1.f - 2.f / (__expf(2.f * x) + 1.f); }

// ---------------------------------------------------------------------------
// Weight prep: permute rows r = (j>>4)*64 + gate*16 + (j&15)  (old = gate*H + j)
// so a 64-wide column group holds 16 units x 4 gates, gate index = n-frag index.
// ---------------------------------------------------------------------------
__global__ void prep_w0(const float* __restrict__ Whh0, unsigned short* __restrict__ Wr) {
  int i = (blockIdx.x * 256 + threadIdx.x) * 4;           // over 4096*1024
  int r = i >> 10, k = i & 1023;
  int gate = (r >> 4) & 3;
  int j = ((r >> 6) << 4) + (r & 15);
  const float4 v = *(const float4*)(Whh0 + (size_t)(gate * H_ + j) * H_ + k);
  ushort4 o; o.x = f2bf(v.x); o.y = f2bf(v.y); o.z = f2bf(v.z); o.w = f2bf(v.w);
  *(ushort4*)(Wr + i) = o;
}

__global__ void prep_wcat(const float* __restrict__ Wih1, const float* __restrict__ Whh1,
                          unsigned short* __restrict__ Wr) {
  int i = (blockIdx.x * 256 + threadIdx.x) * 4;           // over 4096*2048
  int r = i >> 11, k = i & 2047;
  int gate = (r >> 4) & 3;
  int j = ((r >> 6) << 4) + (r & 15);
  const float* src = (k < 1024) ? (Wih1 + (size_t)(gate * H_ + j) * H_ + k)
                                : (Whh1 + (size_t)(gate * H_ + j) * H_ + (k - 1024));
  const float4 v = *(const float4*)src;
  ushort4 o; o.x = f2bf(v.x); o.y = f2bf(v.y); o.z = f2bf(v.z); o.w = f2bf(v.w);
  *(ushort4*)(Wr + (size_t)r * 2048 + k) = o;
}

__global__ void prep_small(const float* __restrict__ Wih0,
                           const float* __restrict__ bih0, const float* __restrict__ bhh0,
                           const float* __restrict__ bih1, const float* __restrict__ bhh1,
                           float* __restrict__ bias0r, float* __restrict__ bias1r,
                           float* __restrict__ wi0r) {
  int r = blockIdx.x * 256 + threadIdx.x;                 // over 4096
  int gate = (r >> 4) & 3;
  int j = ((r >> 6) << 4) + (r & 15);
  int old = gate * H_ + j;
  bias0r[r] = bih0[old] + bhh0[old];
  bias1r[r] = bih1[old] + bhh1[old];
  wi0r[r * 2 + 0] = Wih0[old * 2 + 0];
  wi0r[r * 2 + 1] = Wih0[old * 2 + 1];
}

__global__ void prep_state(const float* __restrict__ h, const float* __restrict__ c,
                           unsigned short* __restrict__ h0b, unsigned short* __restrict__ h1b,
                           float* __restrict__ c0, float* __restrict__ c1, int bh) {
  int i = (blockIdx.x * 256 + threadIdx.x) * 4;           // over B*H
  float4 a = *(const float4*)(h + i);
  float4 b = *(const float4*)(h + (size_t)bh + i);
  ushort4 oa; oa.x = f2bf(a.x); oa.y = f2bf(a.y); oa.z = f2bf(a.z); oa.w = f2bf(a.w);
  ushort4 ob; ob.x = f2bf(b.x); ob.y = f2bf(b.y); ob.z = f2bf(b.z); ob.w = f2bf(b.w);
  *(ushort4*)(h0b + i) = oa;
  *(ushort4*)(h1b + i) = ob;
  *(float4*)(c0 + i) = *(const float4*)(c + i);
  *(float4*)(c1 + i) = *(const float4*)(c + (size_t)bh + i);
}

// ---------------------------------------------------------------------------
// Fused GEMM + LSTM cell (R7 structure: 128x128 tile, BK=64, 4 waves,
// single-buffered swizzled LDS, default block order = best XCD locality).
// Atomic-free fc fusion, TRANSPOSED partial layout (no cross-XCD line sharing):
//  - L1 (fcW != null): epilogue shfl-reduces hn*fcW over the 16 unit-lanes and
//    writes float2 partials to fcpT[jgrp*B + row] — each 64B line = 8 rows of
//    ONE jgrp, written by exactly one block, contiguous 1KB runs.
//  - L0, t>=1 (fcpart_in != null): threads 0..127 sum the 64 jgrp-partials of
//    row tile_m+tid (coalesced across threads), write prev-step logits to
//    outPrev, cache x=argmax flag in LDS for the epilogue's W_ih0 select.
// ---------------------------------------------------------------------------
__global__ void __launch_bounds__(256, 4)
lstm_gemm_cell(const unsigned short* __restrict__ A0,
               const unsigned short* __restrict__ A1,
               int Ktot,
               const unsigned short* __restrict__ Bw,
               const float* __restrict__ biasr,
               const float* __restrict__ wi0r,
               const float* __restrict__ fcpart_in,
               const float* __restrict__ fcb,
               float* __restrict__ outPrev,
               int pl2,
               float* __restrict__ Cst,
               unsigned short* __restrict__ Hout,
               const float* __restrict__ fcW,
               float* __restrict__ fcpart_out) {
  __shared__ unsigned short As[128 * 64];
  __shared__ unsigned short Bs[128 * 64];
  __shared__ unsigned char xflag[128];
  const int tid  = threadIdx.x;
  const int lane = tid & 63;
  const int wv   = tid >> 6;
  const int wm   = wv >> 1, wn = wv & 1;
  const int tile_m = blockIdx.y * 128;
  const int tile_n = blockIdx.x * 128;
  const int Bsz = gridDim.y * 128;                 // total rows (4096)

  // ---- L0 prologue: reduce previous step's fc partials -> x flags + logits ----
  const int have_x = (fcpart_in != nullptr);
  if (have_x && tid < 128) {
    const int row = tile_m + tid;
    float s0 = 0.f, s1 = 0.f;
#pragma unroll 8
    for (int jg = 0; jg < 64; ++jg) {
      float2 v = *(const float2*)(fcpart_in + ((size_t)jg * Bsz + row) * 2);
      s0 += v.x; s1 += v.y;
    }
    s0 += fcb[0]; s1 += fcb[1];
    outPrev[(size_t)row * pl2 + 0] = s0;
    outPrev[(size_t)row * pl2 + 1] = s1;
    xflag[tid] = (s1 > s0) ? 1 : 0;
  }
  // (visibility of xflag guaranteed by the K-loop's __syncthreads below)

  f32x4 acc[4][4];
#pragma unroll
  for (int m = 0; m < 4; ++m)
#pragma unroll
    for (int n = 0; n < 4; ++n) acc[m][n] = (f32x4)0.f;

  // staging: chunk = 8 rows x 64 cols; dest linear, source col slot ^= row&7.
  const int lrow = lane >> 3;
  const int lk   = ((lane & 7) ^ lrow) * 8;

  const int nk = Ktot >> 6;
  for (int kt = 0; kt < nk; ++kt) {
    const int k0 = kt << 6;
    const unsigned short* Ap; int kl;
    if (k0 < 1024) { Ap = A0; kl = k0; } else { Ap = A1; kl = k0 - 1024; }
#pragma unroll
    for (int i = 0; i < 4; ++i) {
      int chunk = wv * 4 + i;
      int row = chunk * 8 + lrow;
      gload_lds16(Ap + (size_t)(tile_m + row) * H_ + kl + lk, (void*)&As[chunk * 512]);
    }
#pragma unroll
    for (int i = 0; i < 4; ++i) {
      int chunk = wv * 4 + i;
      int row = chunk * 8 + lrow;
      gload_lds16(Bw + (size_t)(tile_n + row) * Ktot + k0 + lk, (void*)&Bs[chunk * 512]);
    }
    __syncthreads();

    const char* Ab = (const char*)As;
    const char* Bb = (const char*)Bs;
    const int arow = wm * 64 + (lane & 15);
    const int brow = wn * 64 + (lane & 15);
    const int khi  = lane >> 4;
    const int x7   = lane & 7;
    const int ksw0 = ((0 + khi) ^ x7) * 16;
    const int ksw1 = ((4 + khi) ^ x7) * 16;
#pragma unroll
    for (int ks = 0; ks < 2; ++ks) {
      const int ksw = ks ? ksw1 : ksw0;
      bf16x8 af[4], bfr[4];
#pragma unroll
      for (int m = 0; m < 4; ++m)
        af[m] = *(const bf16x8*)(Ab + (arow + m * 16) * 128 + ksw);
#pragma unroll
      for (int n = 0; n < 4; ++n)
        bfr[n] = *(const bf16x8*)(Bb + (brow + n * 16) * 128 + ksw);
#pragma unroll
      for (int m = 0; m < 4; ++m)
#pragma unroll
        for (int n = 0; n < 4; ++n)
          acc[m][n] = __builtin_amdgcn_mfma_f32_16x16x32_bf16(af[m], bfr[n], acc[m][n], 0, 0, 0);
    }
    __syncthreads();
  }

  // ---- epilogue: fused LSTM cell (+ optional fc partials) ----
  const int cl = lane & 15;
  const int rq = (lane >> 4) * 4;
  const int jgrp = (tile_n >> 6) + wn;             // 16-unit slot index, 0..63
  const int j = jgrp * 16 + cl;
  float bias[4], w0v[4] = {0, 0, 0, 0}, w1v[4] = {0, 0, 0, 0};
#pragma unroll
  for (int n = 0; n < 4; ++n) {
    int colr = tile_n + wn * 64 + n * 16 + cl;
    bias[n] = biasr[colr];
    if (have_x) { w0v[n] = wi0r[colr * 2]; w1v[n] = wi0r[colr * 2 + 1]; }
  }
  float fW0 = 0.f, fW1 = 0.f;
  if (fcW) { fW0 = fcW[j]; fW1 = fcW[H_ + j]; }

#pragma unroll
  for (int m = 0; m < 4; ++m) {
#pragma unroll
    for (int q = 0; q < 4; ++q) {
      int row = tile_m + wm * 64 + m * 16 + rq + q;
      float gi = acc[m][0][q] + bias[0];
      float gf = acc[m][1][q] + bias[1];
      float gg = acc[m][2][q] + bias[2];
      float go = acc[m][3][q] + bias[3];
      if (have_x) {
        int x = xflag[row - tile_m];
        gi += x ? w1v[0] : w0v[0];
        gf += x ? w1v[1] : w0v[1];
        gg += x ? w1v[2] : w0v[2];
        go += x ? w1v[3] : w0v[3];
      }
      size_t off = (size_t)row * H_ + j;
      float cp = Cst[off];
      float cn = sigm(gf) * cp + sigm(gi) * tanh_(gg);
      float hn = sigm(go) * tanh_(cn);
      Cst[off] = cn;
      Hout[off] = f2bf(hn);
      if (fcW) {
        float d0 = hn * fW0, d1 = hn * fW1;
#pragma unroll
        for (int s = 1; s < 16; s <<= 1) {
          d0 += __shfl_xor(d0, s);
          d1 += __shfl_xor(d1, s);
        }
        if (cl == 0) {
          float2 p; p.x = d0; p.y = d1;
          *(float2*)(fcpart_out + ((size_t)jgrp * Bsz + row) * 2) = p;
        }
      }
    }
  }
}

// ---------------------------------------------------------------------------
// final step's fc: reduce transposed partials -> out[:, pred_len-1, :]
// ---------------------------------------------------------------------------
__global__ void fc_finalize(const float* __restrict__ fcpart, const float* __restrict__ fcb,
                            float* __restrict__ outLast, int pl2) {
  const int Bsz = gridDim.x * 256;
  const int row = blockIdx.x * 256 + threadIdx.x;
  float s0 = 0.f, s1 = 0.f;
#pragma unroll 8
  for (int jg = 0; jg < 64; ++jg) {
    float2 v = *(const float2*)(fcpart + ((size_t)jg * Bsz + row) * 2);
    s0 += v.x; s1 += v.y;
  }
  outLast[(size_t)row * pl2 + 0] = s0 + fcb[0];
  outLast[(size_t)row * pl2 + 1] = s1 + fcb[1];
}

// ---------------------------------------------------------------------------
extern "C" void kernel_launch(void* const* d_in, const int* in_sizes, int n_in,
                              void* d_out, int out_size, void* d_ws, size_t ws_size,
                              hipStream_t stream) {
  const float* h     = (const float*)d_in[0];
  const float* c     = (const float*)d_in[1];
  const float* Wih0  = (const float*)d_in[2];
  const float* Whh0  = (const float*)d_in[3];
  const float* bih0  = (const float*)d_in[4];
  const float* bhh0  = (const float*)d_in[5];
  const float* Wih1  = (const float*)d_in[6];
  const float* Whh1  = (const float*)d_in[7];
  const float* bih1  = (const float*)d_in[8];
  const float* bhh1  = (const float*)d_in[9];
  const float* fcW   = (const float*)d_in[10];
  const float* fcb   = (const float*)d_in[11];

  const int B = in_sizes[0] / (2 * H_);           // 4096
  const int pred_len = out_size / (B * 2);        // 64
  const int BH = B * H_;                          // 4194304
  const int pl2 = pred_len * 2;

  size_t off = 0;
  auto carve = [&](size_t bytes) -> void* {
    void* p = (char*)d_ws + off;
    off += (bytes + 255) & ~(size_t)255;
    return p;
  };
  unsigned short* Whh0r = (unsigned short*)carve((size_t)NG_ * 1024 * 2);
  unsigned short* Wcatr = (unsigned short*)carve((size_t)NG_ * 2048 * 2);
  unsigned short* h0b[2], *h1b[2];
  h0b[0] = (unsigned short*)carve((size_t)BH * 2);
  h0b[1] = (unsigned short*)carve((size_t)BH * 2);
  h1b[0] = (unsigned short*)carve((size_t)BH * 2);
  h1b[1] = (unsigned short*)carve((size_t)BH * 2);
  float* c0 = (float*)carve((size_t)BH * 4);
  float* c1 = (float*)carve((size_t)BH * 4);
  float* bias0r = (float*)carve(NG_ * 4);
  float* bias1r = (float*)carve(NG_ * 4);
  float* wi0r   = (float*)carve(NG_ * 2 * 4);
  float* fcpart = (float*)carve((size_t)B * 128 * 4);   // 2 MB, [jgrp][row] float2

  hipLaunchKernelGGL(prep_w0,   dim3((NG_ * 1024 / 4) / 256), dim3(256), 0, stream, Whh0, Whh0r);
  hipLaunchKernelGGL(prep_wcat, dim3((NG_ * 2048 / 4) / 256), dim3(256), 0, stream, Wih1, Whh1, Wcatr);
  hipLaunchKernelGGL(prep_small, dim3(NG_ / 256), dim3(256), 0, stream,
                     Wih0, bih0, bhh0, bih1, bhh1, bias0r, bias1r, wi0r);
  hipLaunchKernelGGL(prep_state, dim3((BH / 4) / 256), dim3(256), 0, stream,
                     h, c, h0b[0], h1b[0], c0, c1, BH);

  dim3 ggrid(NG_ / 128, B / 128);                 // 32 x 32 = 1024 blocks
  dim3 gblk(256);
  float* out = (float*)d_out;

  for (int t = 0; t < pred_len; ++t) {
    const int cur = t & 1, nxt = cur ^ 1;
    // layer 0: gates = h0 @ Whh0^T + bias (+ Wih0[:,x]); also reduces prev fc
    hipLaunchKernelGGL(lstm_gemm_cell, ggrid, gblk, 0, stream,
                       h0b[cur], (const unsigned short*)nullptr, 1024, Whh0r,
                       bias0r, wi0r,
                       (t > 0) ? (const float*)fcpart : (const float*)nullptr,
                       fcb,
                       (t > 0) ? (out + (size_t)(t - 1) * 2) : (float*)nullptr,
                       pl2,
                       c0, h0b[nxt],
                       (const float*)nullptr, (float*)nullptr);
    // layer 1: gates = [h0n|h1] @ Wcat^T + bias; fc partials -> fcpart (transposed)
    hipLaunchKernelGGL(lstm_gemm_cell, ggrid, gblk, 0, stream,
                       h0b[nxt], h1b[cur], 2048, Wcatr,
                       bias1r, (const float*)nullptr,
                       (const float*)nullptr, (const float*)nullptr,
                       (float*)nullptr, pl2,
                       c1, h1b[nxt],
                       fcW, fcpart);
  }
  hipLaunchKernelGGL(fc_finalize, dim3(B / 256), dim3(256), 0, stream,
                     fcpart, fcb, out + (size_t)(pred_len - 1) * 2, pl2);
}